// Round 1
// baseline (338.051 us; speedup 1.0000x reference)
//
#include <hip/hip_runtime.h>
#include <hip/hip_bf16.h>

using u16    = unsigned short;
using short8 = __attribute__((ext_vector_type(8))) short;
using u16x4  = __attribute__((ext_vector_type(4))) u16;
using f32x4  = __attribute__((ext_vector_type(4))) float;

#define M_DIM 8192   // B*S = 16*512
#define N_DIM 1024   // D_OUT
#define K_DIM 4096   // D_IN

typedef __attribute__((address_space(1))) void gvoid;
typedef __attribute__((address_space(3))) void svoid;
#define GLOAD_LDS16(g, s) \
  __builtin_amdgcn_global_load_lds((gvoid*)(void*)(g), (svoid*)(s), 16, 0, 0)

// ---- kernel 1: per-row alpha = mean|W|, Wsgn = sign(W) as bf16 (+1/-1/0 exact)
__global__ __launch_bounds__(256) void wprep_kernel(const float* __restrict__ W,
                                                    u16* __restrict__ Wsgn,
                                                    float* __restrict__ alpha) {
  const int row = blockIdx.x;
  const int t   = threadIdx.x;
  const float4* wr = (const float4*)(W + (size_t)row * K_DIM);
  float4 v[4];
  float s = 0.f;
#pragma unroll
  for (int j = 0; j < 4; ++j) {
    v[j] = wr[t + 256 * j];
    s += fabsf(v[j].x) + fabsf(v[j].y) + fabsf(v[j].z) + fabsf(v[j].w);
  }
#pragma unroll
  for (int off = 32; off > 0; off >>= 1) s += __shfl_down(s, off, 64);
  __shared__ float red[4];
  if ((t & 63) == 0) red[t >> 6] = s;
  __syncthreads();
  if (t == 0) alpha[row] = (red[0] + red[1] + red[2] + red[3]) * (1.0f / K_DIM);
  u16x4* dst = (u16x4*)(Wsgn + (size_t)row * K_DIM);
#pragma unroll
  for (int j = 0; j < 4; ++j) {
    u16x4 sg;
    sg[0] = v[j].x > 0.f ? 0x3F80 : (v[j].x < 0.f ? 0xBF80 : 0);
    sg[1] = v[j].y > 0.f ? 0x3F80 : (v[j].y < 0.f ? 0xBF80 : 0);
    sg[2] = v[j].z > 0.f ? 0x3F80 : (v[j].z < 0.f ? 0xBF80 : 0);
    sg[3] = v[j].w > 0.f ? 0x3F80 : (v[j].w < 0.f ? 0xBF80 : 0);
    dst[t + 256 * j] = sg;
  }
}

// fp32x8 -> bf16x8 (RNE). __float22bfloat162_rn lowers to v_cvt_pk_bf16_f32 on
// gfx950 (native __bf16); rounding is identical to the old f2bf helper.
__device__ __forceinline__ short8 pack_bf16x8(f32x4 lo, f32x4 hi) {
  union { short8 s; __hip_bfloat162 h[4]; } u;
  u.h[0] = __float22bfloat162_rn(make_float2(lo[0], lo[1]));
  u.h[1] = __float22bfloat162_rn(make_float2(lo[2], lo[3]));
  u.h[2] = __float22bfloat162_rn(make_float2(hi[0], hi[1]));
  u.h[3] = __float22bfloat162_rn(make_float2(hi[2], hi[3]));
  return u.s;
}

// ---- kernel 2: GEMM C[m,n] = sum_k A[m,k]*Wsgn[n,k], epilogue *alpha + b + resid
// Round 5: fp32-direct A staging — the separate cast kernel + 64 MiB Abf
// round-trip are gone. A is DMA-staged to LDS as fp32 (32 KB/tile) and
// converted to bf16 in-register while building the MFMA A-fragment.
// LDS layouts (granule = 16 B):
//   lA: [row][16 granules], slot g holds logical granule g ^ (row&7)
//   lB: [row][ 8 granules], slot g holds logical granule g ^ (row&7)
// Swizzle is folded into the per-lane DMA SOURCE address; LDS dest stays
// linear (global_load_lds requirement).
__global__ __launch_bounds__(256) void gemm_kernel(const float* __restrict__ A,
                                                   const u16* __restrict__ Bsgn,
                                                   const float* __restrict__ alpha,
                                                   const float* __restrict__ bias,
                                                   const float* __restrict__ resid,
                                                   float* __restrict__ out) {
  __shared__ float lA[128 * 64];   // 32 KB (fp32)
  __shared__ u16   lB[128 * 64];   // 16 KB (bf16 ±1)
  const int tid  = threadIdx.x;
  const int wave = tid >> 6;
  const int lane = tid & 63;
  const int quad = lane >> 4;
  const int l16  = lane & 15;
  const int wm   = (wave >> 1) * 64;
  const int wn   = (wave & 1) * 64;

  // XCD swizzle: 512 blocks; xcd = b&7 owns M-bands, all 8 N-tiles per band.
  const int b    = blockIdx.x;
  const int xcd  = b & 7;
  const int l    = b >> 3;                        // 0..63
  const size_t m0 = (size_t)(xcd * 8 + (l >> 3)) * 128;
  const size_t n0 = (size_t)(l & 7) * 128;

  f32x4 acc[4][4] = {};

  // B staging: 16 chunks x 1 KB (8 rows x 128 B), 4 per wave.
  const int r8  = lane >> 3;
  const int kgB = ((lane & 7) ^ r8) * 8;          // source k elem offset (bf16)
  // A staging: 32 chunks x 1 KB (4 rows x 256 B), 8 per wave.
  const int r4  = lane >> 4;
  const int gA  = lane & 15;                      // dest granule slot

  const u16*   bsrc[4];
  u16*         bdst[4];
  const float* asrc[8];
  float*       adst[8];
#pragma unroll
  for (int j = 0; j < 4; ++j) {
    const int c = wave * 4 + j;                   // chunk 0..15
    bsrc[j] = Bsgn + (n0 + (size_t)c * 8 + r8) * K_DIM + kgB;
    bdst[j] = lB + c * 512;
  }
#pragma unroll
  for (int j = 0; j < 8; ++j) {
    const int c   = wave * 8 + j;                 // chunk 0..31
    const int row = c * 4 + r4;
    asrc[j] = A + (m0 + row) * (size_t)K_DIM + (gA ^ (row & 7)) * 4;
    adst[j] = lA + c * 256;                       // 1 KB per chunk
  }

  for (int k0 = 0; k0 < K_DIM; k0 += 64) {
#pragma unroll
    for (int j = 0; j < 4; ++j) GLOAD_LDS16(bsrc[j] + k0, bdst[j]);
#pragma unroll
    for (int j = 0; j < 8; ++j) GLOAD_LDS16(asrc[j] + k0, adst[j]);
    asm volatile("s_waitcnt vmcnt(0)" ::: "memory");
    __syncthreads();

#pragma unroll
    for (int s = 0; s < 2; ++s) {
      const int kq = s * 4 + quad;                // k-granule-pair index 0..7
      short8 af[4], bf[4];
#pragma unroll
      for (int mt = 0; mt < 4; ++mt) {
        const int row = wm + mt * 16 + l16;
        const float* rp = lA + row * 64;
        const int sl = (kq * 2) ^ (row & 7);      // slot of even granule
        f32x4 lo = *(const f32x4*)(rp + sl * 4);
        f32x4 hi = *(const f32x4*)(rp + (sl ^ 1) * 4);
        af[mt] = pack_bf16x8(lo, hi);
      }
#pragma unroll
      for (int nt = 0; nt < 4; ++nt) {
        const int col = wn + nt * 16 + l16;
        bf[nt] = *(const short8*)(lB + col * 64 + ((kq ^ (col & 7)) * 8));
      }
#pragma unroll
      for (int mt = 0; mt < 4; ++mt)
#pragma unroll
        for (int nt = 0; nt < 4; ++nt)
          acc[mt][nt] = __builtin_amdgcn_mfma_f32_16x16x32_bf16(af[mt], bf[nt],
                                                                acc[mt][nt], 0, 0, 0);
    }
    __syncthreads();
  }

  // epilogue: x = acc*alpha[n] + b[n] + resid ; C/D map: col=l16, row=quad*4+r
#pragma unroll
  for (int nt = 0; nt < 4; ++nt) {
    const size_t n  = n0 + wn + nt * 16 + l16;
    const float  al = alpha[n];
    const float  bi = bias[n];
#pragma unroll
    for (int mt = 0; mt < 4; ++mt) {
      const size_t mbase = m0 + wm + mt * 16 + quad * 4;
#pragma unroll
      for (int r = 0; r < 4; ++r) {
        const size_t mm = mbase + r;
        out[mm * N_DIM + n] = acc[mt][nt][r] * al + bi + resid[mm * N_DIM + n];
      }
    }
  }
}

// ---- kernel 3: LayerNorm over last dim (1024), in-place on d_out
__global__ __launch_bounds__(256) void ln_kernel(float* __restrict__ x,
                                                 const float* __restrict__ gamma,
                                                 const float* __restrict__ beta) {
  const size_t row = blockIdx.x;
  float4* xr = (float4*)(x + row * N_DIM);
  const int t = threadIdx.x;
  float4 v = xr[t];
  float s  = v.x + v.y + v.z + v.w;
  float sq = v.x * v.x + v.y * v.y + v.z * v.z + v.w * v.w;
#pragma unroll
  for (int off = 32; off > 0; off >>= 1) {
    s  += __shfl_down(s, off, 64);
    sq += __shfl_down(sq, off, 64);
  }
  __shared__ float rs[4], rq[4];
  if ((t & 63) == 0) { rs[t >> 6] = s; rq[t >> 6] = sq; }
  __syncthreads();
  s  = rs[0] + rs[1] + rs[2] + rs[3];
  sq = rq[0] + rq[1] + rq[2] + rq[3];
  const float mu  = s * (1.0f / N_DIM);
  float var = sq * (1.0f / N_DIM) - mu * mu;
  var = fmaxf(var, 0.0f);
  const float inv = rsqrtf(var + 1e-12f);
  const float4 g = ((const float4*)gamma)[t];
  const float4 b = ((const float4*)beta)[t];
  v.x = g.x * ((v.x - mu) * inv) + b.x;
  v.y = g.y * ((v.y - mu) * inv) + b.y;
  v.z = g.z * ((v.z - mu) * inv) + b.z;
  v.w = g.w * ((v.w - mu) * inv) + b.w;
  xr[t] = v;
}

extern "C" void kernel_launch(void* const* d_in, const int* in_sizes, int n_in,
                              void* d_out, int out_size, void* d_ws, size_t ws_size,
                              hipStream_t stream) {
  const float* hidden = (const float*)d_in[0];  // [16,512,4096]
  const float* resid  = (const float*)d_in[1];  // [16,512,1024]
  const float* W      = (const float*)d_in[2];  // [1024,4096]
  const float* bias   = (const float*)d_in[3];  // [1024]
  const float* gamma  = (const float*)d_in[4];  // [1024]
  const float* beta   = (const float*)d_in[5];  // [1024]
  float* out = (float*)d_out;                   // [16,512,1024] fp32

  char* ws = (char*)d_ws;
  u16*   Wsgn  = (u16*)ws;                                   // 8 MiB
  float* alpha = (float*)(ws + 8ull * 1024 * 1024);          // 4 KiB

  wprep_kernel<<<N_DIM, 256, 0, stream>>>(W, Wsgn, alpha);

  const int nblocks = (N_DIM / 128) * (M_DIM / 128);  // 512, 1D swizzled grid
  gemm_kernel<<<nblocks, 256, 0, stream>>>(hidden, Wsgn, alpha, bias, resid, out);

  ln_kernel<<<M_DIM, 256, 0, stream>>>(out, gamma, beta);
}